// Round 8
// baseline (245.683 us; speedup 1.0000x reference)
//
#include <hip/hip_runtime.h>

#define NXD 4096
#define NYD 4096
#define TR 8            // output rows per block
#define TC 1024         // cols per block

typedef float f32x4 __attribute__((ext_vector_type(4)));

#define AS_GLB const __attribute__((address_space(1))) unsigned int
#define AS_LDS __attribute__((address_space(3))) unsigned int

// R8: direct-to-LDS DMA staging (the one untested structural axis).
// Every prior round used the VGPR return path -> DRAM controller sees 4
// streams of finely interleaved reads+writes (bus-turnaround losses), and
// 8 different request-side structures all equilibrated at ~3.3 TB/s vs the
// 6.3-6.7 TB/s homogeneous-burst ubenches. This kernel issues one contiguous
// 80 KB pure-read DMA burst per block (global_load_lds, no VGPR deps), then
// computes from LDS, then one contiguous 64 KB write burst. 80 KB LDS ->
// 2 blocks/CU ping-pong (one computes while the other's DMA flies).
__global__ __launch_bounds__(256) void DiffReactParamPDE_85478439125433_kernel(
    const float* __restrict__ state,
    const float* __restrict__ bc,
    const float* __restrict__ a_org,
    const float* __restrict__ b_org,
    const float* __restrict__ k_org,
    float* __restrict__ out)
{
    const float inv_dx2 = 100.0f;

    __shared__ float sU[TR + 2][TC];
    __shared__ float sV[TR + 2][TC];

    const int tid   = threadIdx.x;             // 0..255
    const int tileX = blockIdx.x & 3;          // 4 col-tiles of 1024
    const int band  = blockIdx.x >> 2;         // 0..511
    const int j0    = tileX * TC + tid * 4;
    const int i0    = band * TR;

    const float* __restrict__ U = state;
    const float* __restrict__ V = state + (size_t)NXD * NYD;
    float* __restrict__ dU = out;
    float* __restrict__ dV = out + (size_t)NXD * NYD;

    // ---- issue the full 80 KB read burst as fire-and-forget DMA ----
    // (10 rows x 2 fields; LDS dest is linear = lane x 16 B, as required)
#pragma unroll
    for (int s = 0; s < TR + 2; ++s) {
        int gr = i0 - 1 + s;
        gr = (gr < 0) ? 0 : ((gr >= NXD) ? NXD - 1 : gr);
        __builtin_amdgcn_global_load_lds(
            (AS_GLB*)(U + (size_t)gr * NYD + j0),
            (AS_LDS*)&sU[s][tid * 4], 16, 0, 0);
        __builtin_amdgcn_global_load_lds(
            (AS_GLB*)(V + (size_t)gr * NYD + j0),
            (AS_LDS*)&sV[s][tid * 4], 16, 0, 0);
    }

    // ---- scalar params + bc on the scalar pipe while the DMA flies ----
    const float uL = bc[0], uR = bc[1], uT = bc[2], uB = bc[3];
    const float vL = bc[4], vR = bc[5], vT = bc[6], vB = bc[7];
    const float a = 0.01f / (1.0f + expf(-a_org[0]));
    const float b = 0.01f / (1.0f + expf(-b_org[0]));
    const float k = 0.01f / (1.0f + expf(-k_org[0]));

    // ---- tile-edge columns into registers (threads 0 / 255 only) ----
    float eu[TR], ev[TR];
#pragma unroll
    for (int r = 0; r < TR; ++r) {
        eu[r] = (tid == 0) ? uL : uR;
        ev[r] = (tid == 0) ? vL : vR;
    }
    if (tid == 0 && tileX > 0) {
        const int jl = tileX * TC - 1;
#pragma unroll
        for (int r = 0; r < TR; ++r) {
            eu[r] = U[(size_t)(i0 + r) * NYD + jl];
            ev[r] = V[(size_t)(i0 + r) * NYD + jl];
        }
    }
    if (tid == 255 && tileX < 3) {
        const int jr = tileX * TC + TC;
#pragma unroll
        for (int r = 0; r < TR; ++r) {
            eu[r] = U[(size_t)(i0 + r) * NYD + jr];
            ev[r] = V[(size_t)(i0 + r) * NYD + jr];
        }
    }

    __syncthreads();   // vmcnt(0)+barrier: LDS tile fully staged

    const float4 fuT = make_float4(uT, uT, uT, uT), fuB4 = make_float4(uB, uB, uB, uB);
    const float4 fvT = make_float4(vT, vT, vT, vT), fvB4 = make_float4(vB, vB, vB, vB);

#pragma unroll
    for (int r = 0; r < TR; ++r) {
        const int s   = r + 1;
        const int row = i0 + r;
        const int c   = tid * 4;

        float4 uc = *(const float4*)&sU[s][c];
        float4 um = *(const float4*)&sU[s - 1][c];
        float4 up = *(const float4*)&sU[s + 1][c];
        float4 vc = *(const float4*)&sV[s][c];
        float4 vm = *(const float4*)&sV[s - 1][c];
        float4 vp = *(const float4*)&sV[s + 1][c];

        // true domain boundary patches (block-uniform at band 0 / 511)
        if (row == 0)       { um = fuT;  vm = fvT;  }
        if (row == NXD - 1) { up = fuB4; vp = fvB4; }

        // horizontal neighbors straight from LDS (2-way bank alias = free);
        // tile-edge columns from the register scalars on threads 0/255.
        const float ulft = (tid == 0)   ? eu[r] : sU[s][c - 1];
        const float urgt = (tid == 255) ? eu[r] : sU[s][c + 4];
        const float vlft = (tid == 0)   ? ev[r] : sV[s][c - 1];
        const float vrgt = (tid == 255) ? ev[r] : sV[s][c + 4];

        const float lu0 = (um.x + up.x + ulft + uc.y - 4.0f * uc.x) * inv_dx2;
        const float lu1 = (um.y + up.y + uc.x + uc.z - 4.0f * uc.y) * inv_dx2;
        const float lu2 = (um.z + up.z + uc.y + uc.w - 4.0f * uc.z) * inv_dx2;
        const float lu3 = (um.w + up.w + uc.z + urgt - 4.0f * uc.w) * inv_dx2;

        const float lv0 = (vm.x + vp.x + vlft + vc.y - 4.0f * vc.x) * inv_dx2;
        const float lv1 = (vm.y + vp.y + vc.x + vc.z - 4.0f * vc.y) * inv_dx2;
        const float lv2 = (vm.z + vp.z + vc.y + vc.w - 4.0f * vc.z) * inv_dx2;
        const float lv3 = (vm.w + vp.w + vc.z + vrgt - 4.0f * vc.w) * inv_dx2;

        f32x4 duo, dvo;
        duo.x = a * lu0 + uc.x - uc.x * uc.x * uc.x - vc.x - k;
        duo.y = a * lu1 + uc.y - uc.y * uc.y * uc.y - vc.y - k;
        duo.z = a * lu2 + uc.z - uc.z * uc.z * uc.z - vc.z - k;
        duo.w = a * lu3 + uc.w - uc.w * uc.w * uc.w - vc.w - k;

        dvo.x = b * lv0 + uc.x - vc.x;
        dvo.y = b * lv1 + uc.y - vc.y;
        dvo.z = b * lv2 + uc.z - vc.z;
        dvo.w = b * lv3 + uc.w - vc.w;

        const size_t bo = (size_t)row * NYD + j0;
        *(f32x4*)(dU + bo) = duo;
        *(f32x4*)(dV + bo) = dvo;
    }
}

extern "C" void kernel_launch(void* const* d_in, const int* in_sizes, int n_in,
                              void* d_out, int out_size, void* d_ws, size_t ws_size,
                              hipStream_t stream) {
    const float* state = (const float*)d_in[0];
    const float* bc    = (const float*)d_in[1];
    const float* a_org = (const float*)d_in[2];
    const float* b_org = (const float*)d_in[3];
    const float* k_org = (const float*)d_in[4];
    float* out = (float*)d_out;

    // 4 col-tiles x 512 row-bands = 2048 blocks of 256 threads.
    dim3 block(256, 1, 1);
    dim3 grid((NYD / TC) * (NXD / TR), 1, 1);
    DiffReactParamPDE_85478439125433_kernel<<<grid, block, 0, stream>>>(
        state, bc, a_org, b_org, k_org, out);
}